// Round 1
// baseline (589.204 us; speedup 1.0000x reference)
//
#include <hip/hip_runtime.h>
#include <math.h>

// Problem constants (fixed by setup_inputs)
#define BI 64
#define RR 36
#define DD 512
#define BC 64
#define WW 50
#define HH 256
#define TEMP_INV 10.0f
#define MASKV -1.0f
#define EPSV 1e-12f

// ---------------------------------------------------------------------------
// Kernel 1: fused  h = relu(imgs@W1+b1);  unc = sigmoid(h@W2+b2);  img norms
// block = (i, group of 4 rows), 256 threads (thread t = hidden column)
// ---------------------------------------------------------------------------
__global__ __launch_bounds__(256) void k_prep(
    const float* __restrict__ imgs, const float* __restrict__ W1,
    const float* __restrict__ b1, const float* __restrict__ W2,
    const float* __restrict__ b2, float* __restrict__ unc,
    float* __restrict__ nrm) {
  int i = blockIdx.y;
  int r0 = blockIdx.x * 4;
  int t = threadIdx.x, lane = t & 63, wv = t >> 6;
  __shared__ __align__(16) float im[4][DD];
  __shared__ float part[8][4];

  // stage 4 img rows (2048 floats = 512 float4)
  for (int q = t; q < 512; q += 256) {
    int rr = q >> 7;
    int dq = (q & 127) << 2;
    *(float4*)&im[rr][dq] = *(const float4*)&imgs[(i * RR + r0 + rr) * DD + dq];
  }
  __syncthreads();

  float a0 = 0.f, a1 = 0.f, a2 = 0.f, a3 = 0.f;
  for (int d = 0; d < DD; ++d) {
    float w = W1[d * HH + t];  // coalesced across t
    a0 = fmaf(im[0][d], w, a0);
    a1 = fmaf(im[1][d], w, a1);
    a2 = fmaf(im[2][d], w, a2);
    a3 = fmaf(im[3][d], w, a3);
  }
  float bb = b1[t], w2 = W2[t];
  float v[4];
  v[0] = fmaxf(a0 + bb, 0.f) * w2;
  v[1] = fmaxf(a1 + bb, 0.f) * w2;
  v[2] = fmaxf(a2 + bb, 0.f) * w2;
  v[3] = fmaxf(a3 + bb, 0.f) * w2;
  float n[4];
#pragma unroll
  for (int p = 0; p < 4; ++p) {
    float x0 = im[p][t], x1 = im[p][t + 256];
    n[p] = x0 * x0 + x1 * x1;
  }
#pragma unroll
  for (int m = 1; m < 64; m <<= 1) {
#pragma unroll
    for (int p = 0; p < 4; ++p) {
      v[p] += __shfl_xor(v[p], m);
      n[p] += __shfl_xor(n[p], m);
    }
  }
  if (lane == 0) {
#pragma unroll
    for (int p = 0; p < 4; ++p) {
      part[p][wv] = v[p];
      part[4 + p][wv] = n[p];
    }
  }
  __syncthreads();
  if (t < 8) {
    float s = part[t][0] + part[t][1] + part[t][2] + part[t][3];
    if (t < 4)
      unc[i * RR + r0 + t] = 1.f / (1.f + __expf(-(s + b2[0])));
    else
      nrm[i * RR + r0 + (t - 4)] = sqrtf(s);
  }
}

// ---------------------------------------------------------------------------
// Kernel 2: Gram matrices G[j][w][w'] = caps[j,w] . caps[j,w']
// grid (4 pair-groups, 64 j), 256 threads
// ---------------------------------------------------------------------------
__global__ __launch_bounds__(256) void k_gram(const float* __restrict__ caps,
                                              float* __restrict__ G) {
  int j = blockIdx.y, pg = blockIdx.x;
  int t = threadIdx.x;
  __shared__ __align__(16) float cs[128 * 52];  // d-major, pad 50->52
  float acc[3] = {0.f, 0.f, 0.f};
  int base = pg * 625;

  for (int c = 0; c < 4; ++c) {
    int d0 = c * 128;
    for (int q = t; q < 1600; q += 256) {  // 50 rows x 32 float4
      int w = q >> 5;
      int dq = (q & 31) << 2;
      float4 v = *(const float4*)&caps[(j * WW + w) * DD + d0 + dq];
      cs[(dq + 0) * 52 + w] = v.x;
      cs[(dq + 1) * 52 + w] = v.y;
      cs[(dq + 2) * 52 + w] = v.z;
      cs[(dq + 3) * 52 + w] = v.w;
    }
    __syncthreads();
#pragma unroll
    for (int pi = 0; pi < 3; ++pi) {
      int p = base + t + pi * 256;
      if (t + pi * 256 < 625) {
        int w = p / WW, wp = p % WW;
        float a = acc[pi];
        for (int d = 0; d < 128; ++d)
          a = fmaf(cs[d * 52 + w], cs[d * 52 + wp], a);
        acc[pi] = a;
      }
    }
    __syncthreads();
  }
#pragma unroll
  for (int pi = 0; pi < 3; ++pi) {
    int p = base + t + pi * 256;
    if (t + pi * 256 < 625) G[j * 2500 + p] = acc[pi];
  }
}

// ---------------------------------------------------------------------------
// Kernel 3: main — per (i,j) block: sims (36x50, D=512) + attention epilogue
// ---------------------------------------------------------------------------
__global__ __launch_bounds__(256) void k_main(
    const float* __restrict__ imgs, const float* __restrict__ caps,
    const int* __restrict__ img_lens, const int* __restrict__ cap_lens,
    const float* __restrict__ unc, const float* __restrict__ nrm,
    const float* __restrict__ G, float* __restrict__ out) {
  __shared__ __align__(16) float a_s[128 * 40];  // imgs chunk, d-major pad 36->40
  __shared__ __align__(16) float b_s[128 * 52];  // caps chunk, d-major pad 50->52
  __shared__ __align__(16) float sim_s[RR * 52];
  __shared__ float mrow[4 * 64];

  int bid = blockIdx.x;
  int g = bid >> 6, u = bid & 63;
  int i = ((g >> 3) << 3) | (u & 7);   // XCD-friendly: same-XCD blocks share i
  int j = ((g & 7) << 3) | (u >> 3);
  int t = threadIdx.x, lane = t & 63, wv = t >> 6;

  float acc[2][4] = {{0.f, 0.f, 0.f, 0.f}, {0.f, 0.f, 0.f, 0.f}};
  int rg = t / 13, wg = t % 13;  // 18 x 13 = 234 active compute threads
  int r0 = rg * 2, w0 = wg * 4;
  bool active = (t < 234);

  for (int c = 0; c < 4; ++c) {
    int d0 = c * 128;
    // stage imgs[i] chunk transposed: 36 rows x 32 float4
    for (int q = t; q < 1152; q += 256) {
      int r = q >> 5;
      int dq = (q & 31) << 2;
      float4 v = *(const float4*)&imgs[(i * RR + r) * DD + d0 + dq];
      a_s[(dq + 0) * 40 + r] = v.x;
      a_s[(dq + 1) * 40 + r] = v.y;
      a_s[(dq + 2) * 40 + r] = v.z;
      a_s[(dq + 3) * 40 + r] = v.w;
    }
    // stage caps[j] chunk transposed: 50 rows x 32 float4
    for (int q = t; q < 1600; q += 256) {
      int w = q >> 5;
      int dq = (q & 31) << 2;
      float4 v = *(const float4*)&caps[(j * WW + w) * DD + d0 + dq];
      b_s[(dq + 0) * 52 + w] = v.x;
      b_s[(dq + 1) * 52 + w] = v.y;
      b_s[(dq + 2) * 52 + w] = v.z;
      b_s[(dq + 3) * 52 + w] = v.w;
    }
    __syncthreads();
    if (active) {
      for (int d = 0; d < 128; ++d) {
        float2 a = *(const float2*)&a_s[d * 40 + r0];
        float4 b = *(const float4*)&b_s[d * 52 + w0];
        acc[0][0] = fmaf(a.x, b.x, acc[0][0]);
        acc[0][1] = fmaf(a.x, b.y, acc[0][1]);
        acc[0][2] = fmaf(a.x, b.z, acc[0][2]);
        acc[0][3] = fmaf(a.x, b.w, acc[0][3]);
        acc[1][0] = fmaf(a.y, b.x, acc[1][0]);
        acc[1][1] = fmaf(a.y, b.y, acc[1][1]);
        acc[1][2] = fmaf(a.y, b.z, acc[1][2]);
        acc[1][3] = fmaf(a.y, b.w, acc[1][3]);
      }
    }
    __syncthreads();
  }
  if (active) {
#pragma unroll
    for (int p = 0; p < 2; ++p)
#pragma unroll
      for (int q = 0; q < 4; ++q) sim_s[(r0 + p) * 52 + (w0 + q)] = acc[p][q];
  }
  __syncthreads();
  // stage G_j over a_s (10 KB <= 20.5 KB)
  for (int q = t; q < 2500; q += 256) a_s[q] = G[j * 2500 + q];
  __syncthreads();

  int ilen = img_lens[i];
  int cl = cap_lens[j];
  if (cl > WW) cl = WW;

  for (int it = 0; it < 9; ++it) {
    int r = it * 4 + wv;  // each wave owns one row per iteration
    bool rvalid = (r < ilen);
    bool valid = (lane < cl);
    float s = valid ? sim_s[r * 52 + lane] : -INFINITY;
    // masked max over w
    float m = s;
#pragma unroll
    for (int mm = 1; mm < 64; mm <<= 1) m = fmaxf(m, __shfl_xor(m, mm));
    // first argmax index (np semantics)
    int cand = (valid && s == m) ? lane : 1000;
#pragma unroll
    for (int mm = 1; mm < 64; mm <<= 1) {
      int o = __shfl_xor(cand, mm);
      cand = (o < cand) ? o : cand;
    }
    // softmax (temperature 0.1)
    float e = valid ? __expf((s - m) * TEMP_INV) : 0.f;
    float dn = e;
#pragma unroll
    for (int mm = 1; mm < 64; mm <<= 1) dn += __shfl_xor(dn, mm);
    float alpha = unc[i * RR + r];
    float p = alpha * (e / dn);
    // hard attention contributes only if the max beats the mask value
    if (m > MASKV && lane == cand) p += (1.f - alpha);
    float sm = valid ? s : 0.f;
    float num = p * sm;
#pragma unroll
    for (int mm = 1; mm < 64; mm <<= 1) num += __shfl_xor(num, mm);
    mrow[wv * 64 + lane] = p;
    __syncthreads();
    // quadratic form pᵀ G p
    float tq = 0.f;
    if (lane < WW) {
      for (int ww = 0; ww < WW; ++ww)
        tq = fmaf(mrow[wv * 64 + ww], a_s[ww * WW + lane], tq);
    }
    float qd = p * tq;
#pragma unroll
    for (int mm = 1; mm < 64; mm <<= 1) qd += __shfl_xor(qd, mm);
    if (lane == 0) {
      float res;
      if (!rvalid) {
        res = MASKV;
      } else {
        float ni = fmaxf(nrm[i * RR + r], EPSV);
        float nw = fmaxf(sqrtf(qd), EPSV);
        res = num / (ni * nw);
      }
      out[(i * BC + j) * RR + r] = res;
    }
    __syncthreads();
  }
}

extern "C" void kernel_launch(void* const* d_in, const int* in_sizes, int n_in,
                              void* d_out, int out_size, void* d_ws,
                              size_t ws_size, hipStream_t stream) {
  const float* imgs = (const float*)d_in[0];
  const float* caps = (const float*)d_in[1];
  const int* img_lens = (const int*)d_in[2];
  const int* cap_lens = (const int*)d_in[3];
  const float* W1 = (const float*)d_in[4];
  const float* b1 = (const float*)d_in[5];
  const float* W2 = (const float*)d_in[6];
  const float* b2 = (const float*)d_in[7];
  float* out = (float*)d_out;
  float* ws = (float*)d_ws;
  float* unc = ws;           // 2304 floats
  float* nrm = ws + 2304;    // 2304 floats
  float* G = ws + 4608;      // 64*2500 = 160000 floats (~658 KB total)

  hipLaunchKernelGGL(k_prep, dim3(9, 64), dim3(256), 0, stream, imgs, W1, b1,
                     W2, b2, unc, nrm);
  hipLaunchKernelGGL(k_gram, dim3(4, 64), dim3(256), 0, stream, caps, G);
  hipLaunchKernelGGL(k_main, dim3(4096), dim3(256), 0, stream, imgs, caps,
                     img_lens, cap_lens, unc, nrm, G, out);
}